// Round 3
// baseline (195.994 us; speedup 1.0000x reference)
//
#include <hip/hip_runtime.h>

// TemporalShift, residual mode == pure shift:
// x: (B=8, T=16, C=256, H=56, W=56) float32 contiguous.
// out[b,t,c] = x[b,t-1,c]  for c in [0,16)   (0 at t=0)
//            = x[b,t+1,c]  for c in [16,32)  (0 at t=15)
//            = x[b,t,c]    for c >= 32
//
// float4 view: HW = 3136 floats = 784 float4/plane; time stride = 200704 float4.
// Total float4 = 25,690,112 = 2048 blocks * 256 threads * 49 iters EXACTLY.
// R2: keep 7-deep load batching (MLP), DROP nontemporal hints (R1 post-timing
// divergence suspect + slowdown suspect).

typedef float f4 __attribute__((ext_vector_type(4)));

#define TS_HW4    784u
#define TS_CHW4   200704           // 256 * 784 (float4 per time step)
#define NTHREADS  (2048u * 256u)   // 524288 threads total
#define BATCH     7
#define NBATCH    7                // 7 * 7 = 49 iterations/thread

__global__ __launch_bounds__(256) void
ts_kernel(const f4* __restrict__ x, f4* __restrict__ out) {
    unsigned base = blockIdx.x * 256u + threadIdx.x;

    #pragma unroll 1
    for (int blk = 0; blk < NBATCH; ++blk) {
        f4 v[BATCH];

        // Issue BATCH independent loads (7 outstanding 16B loads per lane).
        #pragma unroll
        for (int j = 0; j < BATCH; ++j) {
            const unsigned idx   = base + (unsigned)j * NTHREADS;
            const unsigned plane = idx / TS_HW4;        // magic-mul
            const unsigned c     = plane & 255u;
            const unsigned t     = (plane >> 8) & 15u;  // C=256, T=16 pow2
            const bool fwd  = c < 16u;
            const bool bwd  = (c - 16u) < 16u;          // 16 <= c < 32
            const bool zero = (fwd && t == 0u) || (bwd && t == 15u);
            const int  d    = fwd ? -TS_CHW4 : (bwd ? TS_CHW4 : 0);
            // Boundary lanes load their own (valid) slot, then get zeroed.
            const unsigned src = zero ? idx : (unsigned)((int)idx + d);
            v[j] = x[src];
            if (zero) v[j] = (f4){0.f, 0.f, 0.f, 0.f};  // cndmask, no divergence
        }

        // Drain with staged vmcnt waits.
        #pragma unroll
        for (int j = 0; j < BATCH; ++j) {
            out[base + (unsigned)j * NTHREADS] = v[j];
        }

        base += (unsigned)BATCH * NTHREADS;
    }
}

extern "C" void kernel_launch(void* const* d_in, const int* in_sizes, int n_in,
                              void* d_out, int out_size, void* d_ws, size_t ws_size,
                              hipStream_t stream) {
    const f4* x = (const f4*)d_in[0];
    f4* out = (f4*)d_out;
    // 2048 blocks = 8 blocks/CU on 256 CUs; 49 float4/thread, zero tail.
    ts_kernel<<<2048, 256, 0, stream>>>(x, out);
}

// Round 4
// 166.616 us; speedup vs baseline: 1.1763x; 1.1763x over previous
//
#include <hip/hip_runtime.h>

// TemporalShift, residual mode == pure shift:
// x: (B=8, T=16, C=256, H=56, W=56) float32 contiguous.
// out[b,t,c] = x[b,t-1,c]  for c in [0,16)   (0 at t=0)
//            = x[b,t+1,c]  for c in [16,32)  (0 at t=15)
//            = x[b,t,c]    for c >= 32
//
// float4 view: 784 f4/plane, 200704 f4/time-step, 25,690,112 f4 total.
// Key structure fact: fwd region per (b,t) = 12544 f4 = 49*256, bwd likewise,
// stay = 686*256, CHW4 = 784*256 -> every 256-f4 segment is uniform in
// (class, t). Segment index logic is therefore block-uniform -> SALU.
//
// R3 vs R0: identical coordinated-sweep address pattern (grid stride = 8 MB
// windows), but class/offset/zero logic scalarized, and nontemporal LOADS
// only (stores stay normal — R1 showed nt stores lose writes across graph
// replays).

typedef float f4 __attribute__((ext_vector_type(4)));

#define TS_CHW4   200704           // f4 per time step
#define NSEG      100352u          // total 256-f4 segments = 25690112/256
#define GRID      2048u
#define NITER     49               // NSEG / GRID exactly

__global__ __launch_bounds__(256) void
ts_kernel(const f4* __restrict__ x, f4* __restrict__ out) {
    const unsigned tid = threadIdx.x;
    const unsigned bid = blockIdx.x;

    #pragma unroll 1
    for (int k = 0; k < NITER; ++k) {
        // Everything below except the final load/store is block-uniform (SALU).
        const unsigned seg = (unsigned)k * GRID + bid;   // 256-f4 segment id
        const unsigned bt  = seg / 784u;                 // (b*16+t), magic-mul
        const unsigned r   = seg - bt * 784u;            // segment within plane-set
        const unsigned t   = bt & 15u;
        const bool fwd  = r < 49u;                       // c in [0,16)
        const bool bwd  = !fwd && r < 98u;               // c in [16,32)
        const bool zero = (fwd && t == 0u) || (bwd && t == 15u);
        const int  d    = fwd ? -TS_CHW4 : (bwd ? TS_CHW4 : 0);

        const unsigned i = seg * 256u + tid;             // this thread's f4
        f4 v = (f4){0.f, 0.f, 0.f, 0.f};
        if (!zero) {                                     // scalar branch: skip load
            v = __builtin_nontemporal_load(&x[(unsigned)((int)i + d)]);
        }
        out[i] = v;                                      // normal (cached) store
    }
}

extern "C" void kernel_launch(void* const* d_in, const int* in_sizes, int n_in,
                              void* d_out, int out_size, void* d_ws, size_t ws_size,
                              hipStream_t stream) {
    const f4* x = (const f4*)d_in[0];
    f4* out = (f4*)d_out;
    // 2048 blocks = 8 blocks/CU; 49 segments per block, zero tail.
    ts_kernel<<<GRID, 256, 0, stream>>>(x, out);
}

// Round 5
// 140.617 us; speedup vs baseline: 1.3938x; 1.1849x over previous
//
#include <hip/hip_runtime.h>

// TemporalShift, residual mode == pure shift:
// x: (B=8, T=16, C=256, H=56, W=56) float32 contiguous.
// out[b,t,c] = x[b,t-1,c]  for c in [0,16)   (0 at t=0)
//            = x[b,t+1,c]  for c in [16,32)  (0 at t=15)
//            = x[b,t,c]    for c >= 32
//
// float4 view: 784 f4/plane, 200704 f4/time-step, 25,690,112 f4 total
//            = 100352 segments of 256 f4 (each segment uniform in class,t).
//
// R4: zero-loop streaming — ONE f4 per thread, ONE segment per block.
// seg == blockIdx.x, so all shift logic is SALU on a uniform value; each
// wave issues exactly 1 load + 1 store (no in-wave load->vmcnt(0)->store
// serialization, which R0-R3 all shared). Consecutive blocks sweep
// consecutive 4KB -> linear DRAM sweep driven by the block dispatcher.

typedef float f4 __attribute__((ext_vector_type(4)));

#define TS_CHW4   200704           // f4 per time step
#define NSEG      100352u          // 25,690,112 / 256

__global__ __launch_bounds__(256) void
ts_kernel(const f4* __restrict__ x, f4* __restrict__ out) {
    const unsigned seg = blockIdx.x;                 // one 256-f4 segment
    // Block-uniform (SALU) classification:
    const unsigned bt = seg / 784u;                  // b*16 + t
    const unsigned r  = seg - bt * 784u;             // 256-f4 segment within (b,t)
    const unsigned t  = bt & 15u;
    const bool fwd  = r < 49u;                       // channels [0,16)
    const bool bwd  = !fwd && r < 98u;               // channels [16,32)
    const bool zero = (fwd && t == 0u) || (bwd && t == 15u);
    const int  d    = fwd ? -TS_CHW4 : (bwd ? TS_CHW4 : 0);

    const unsigned i = seg * 256u + threadIdx.x;     // this thread's f4
    f4 v = (f4){0.f, 0.f, 0.f, 0.f};
    if (!zero) {                                     // uniform branch
        v = x[(unsigned)((int)i + d)];
    }
    out[i] = v;
}

extern "C" void kernel_launch(void* const* d_in, const int* in_sizes, int n_in,
                              void* d_out, int out_size, void* d_ws, size_t ws_size,
                              hipStream_t stream) {
    const f4* x = (const f4*)d_in[0];
    f4* out = (f4*)d_out;
    ts_kernel<<<NSEG, 256, 0, stream>>>(x, out);     // 100352 blocks, zero tail
}